// Round 2
// baseline (91593.170 us; speedup 1.0000x reference)
//
#include <hip/hip_runtime.h>
#include <stdint.h>

// Set2Set encoder, MI355X.  (Round 1: unchanged resubmit — round 0 bench was
// an infra GPUAcquisitionTimeout; no data on this kernel yet.)
// Design: 1 block per batch element (256 blocks = 1/CU), 512 threads (8 waves).
//  - x[b] pinned in VGPRs as f16 pairs: xr[16][8] u32 = 128 VGPRs/thread.
//    wave w owns d-slice [16w,16w+16); lane l owns rows {64i+l, i=0..15}.
//  - W1 = W_ih[:, :128] + W_hh folded to f16, column-major in LDS (128 KB),
//    conflict-free reads/writes (consecutive lanes -> consecutive addrs).
//  - W2 = W_ih[:, 128:] as f16x2 column-major in d_ws (prep kernel), coalesced
//    per-step L2 reads. Fallback to f32 direct reads if ws too small.
//  - e/softmax/r fully on-chip; cross-wave e-reduce via 16 KB LDS in 2 chunks.

typedef _Float16 h2f __attribute__((ext_vector_type(2)));

#ifndef __has_builtin
#define __has_builtin(x) 0
#endif

__device__ __forceinline__ uint32_t pack_h2(float a, float b){
  h2f v; v[0] = (_Float16)a; v[1] = (_Float16)b;
  return __builtin_bit_cast(uint32_t, v);
}

__device__ __forceinline__ float fdot2u(uint32_t a, uint32_t b, float c){
  h2f ah = __builtin_bit_cast(h2f, a), bh = __builtin_bit_cast(h2f, b);
#if __has_builtin(__builtin_amdgcn_fdot2)
  return __builtin_amdgcn_fdot2(ah, bh, c, false);
#else
  return c + (float)ah[0]*(float)bh[0] + (float)ah[1]*(float)bh[1];
#endif
}

__device__ __forceinline__ float sigmoidf_(float x){
  return 1.0f / (1.0f + __expf(-x));
}

struct SMem {
  uint32_t w1[64][512];          // 128 KB: W1 f16x2, column-major: w1[kp][j]
  float epart[8][512];           // 16 KB: cross-wave e partials (2 chunks)
  float p[1024];                 // 4 KB: softmax numerators
  float g[512];                  // gates
  float h[128];
  float r[128];
  alignas(16) _Float16 h2a[128]; // packed f16 copy of h (q)
  alignas(16) _Float16 r2a[128]; // packed f16 copy of r
  float redm[8];
  float reds[8];
};                               // ~152 KB total (< 160 KB)

__global__ void prep_w2_kernel(const float* __restrict__ Wih, uint32_t* __restrict__ w2cm){
  int idx = blockIdx.x * blockDim.x + threadIdx.x;   // 64*512 entries
  if (idx < 64*512){
    int kp = idx >> 9, j = idx & 511;
    w2cm[idx] = pack_h2(Wih[j*256 + 128 + 2*kp], Wih[j*256 + 128 + 2*kp + 1]);
  }
}

__global__ __launch_bounds__(512, 2)
void s2s_kernel(const float* __restrict__ x, const float* __restrict__ Wih,
                const float* __restrict__ Whh, const float* __restrict__ bih,
                const float* __restrict__ bhh, const float* __restrict__ Wlin,
                const float* __restrict__ blin, const uint32_t* __restrict__ w2cm,
                int usew2, float* __restrict__ out)
{
  __shared__ SMem sm;
  const int tid = threadIdx.x;
  const int w = tid >> 6, l = tid & 63;
  const int b = blockIdx.x;

  // ---- load x[b] into registers as f16 pairs (one-time HBM read) ----
  uint32_t xr[16][8];
  {
    const float* xb = x + (size_t)b*1024*128 + 16*w;
    #pragma unroll
    for (int i = 0; i < 16; ++i){
      const float* row = xb + (size_t)(i*64 + l)*128;
      #pragma unroll
      for (int j = 0; j < 8; ++j){
        float2 v = *(const float2*)(row + 2*j);
        xr[i][j] = pack_h2(v.x, v.y);
      }
    }
  }
  // ---- fold W1 = W_ih[:, :128] + W_hh into LDS (f16x2, column-major) ----
  {
    const float* wi = Wih + (size_t)tid*256;
    const float* wh = Whh + (size_t)tid*128;
    #pragma unroll 8
    for (int kp = 0; kp < 64; ++kp){
      sm.w1[kp][tid] = pack_h2(wi[2*kp] + wh[2*kp], wi[2*kp+1] + wh[2*kp+1]);
    }
  }
  const float biasj = bih[tid] + bhh[tid];
  if (tid < 128){
    sm.h[tid] = 0.f; sm.r[tid] = 0.f;
    sm.h2a[tid] = (_Float16)0.f; sm.r2a[tid] = (_Float16)0.f;
  }
  float creg = 0.f;   // LSTM cell state, owned by threads 0..127
  __syncthreads();

  #pragma unroll 1
  for (int t = 0; t < 1024; ++t){
    // ---- gates[j] = biasj + W1[j]·h + W2[j]·r  (thread tid = gate j) ----
    float acc = biasj;
    {
      const uint4* hp = (const uint4*)sm.h2a;   // broadcast reads
      #pragma unroll
      for (int k8 = 0; k8 < 16; ++k8){
        uint4 hv = hp[k8];
        acc = fdot2u(sm.w1[4*k8+0][tid], hv.x, acc);
        acc = fdot2u(sm.w1[4*k8+1][tid], hv.y, acc);
        acc = fdot2u(sm.w1[4*k8+2][tid], hv.z, acc);
        acc = fdot2u(sm.w1[4*k8+3][tid], hv.w, acc);
      }
    }
    if (usew2){
      const uint4* rp = (const uint4*)sm.r2a;
      #pragma unroll
      for (int k8 = 0; k8 < 16; ++k8){
        uint4 rv = rp[k8];
        acc = fdot2u(w2cm[(4*k8+0)*512 + tid], rv.x, acc);
        acc = fdot2u(w2cm[(4*k8+1)*512 + tid], rv.y, acc);
        acc = fdot2u(w2cm[(4*k8+2)*512 + tid], rv.z, acc);
        acc = fdot2u(w2cm[(4*k8+3)*512 + tid], rv.w, acc);
      }
    } else {
      const float* wi2 = Wih + (size_t)tid*256 + 128;
      #pragma unroll 8
      for (int kp = 0; kp < 64; ++kp){
        float2 wv = *(const float2*)(wi2 + 2*kp);
        acc += wv.x*sm.r[2*kp] + wv.y*sm.r[2*kp+1];
      }
    }
    sm.g[tid] = acc;
    __syncthreads();                              // B1: gates visible
    // ---- LSTM pointwise (PyTorch gate order i,f,g,o) ----
    if (tid < 128){
      float gi = sm.g[tid], gf = sm.g[128+tid], gc = sm.g[256+tid], go = sm.g[384+tid];
      creg = sigmoidf_(gf)*creg + sigmoidf_(gi)*tanhf(gc);
      float hh = sigmoidf_(go)*tanhf(creg);
      sm.h[tid]  = hh;
      sm.h2a[tid] = (_Float16)hh;
    }
    __syncthreads();                              // B2: h, h2a visible
    // ---- e[n] = x[n]·q : per-thread partials over own d-slice ----
    float ep[16];
    {
      uint4 q0 = *(const uint4*)&sm.h2a[16*w];
      uint4 q1 = *(const uint4*)&sm.h2a[16*w + 8];
      #pragma unroll
      for (int i = 0; i < 16; ++i){
        float e = 0.f;
        e = fdot2u(xr[i][0], q0.x, e); e = fdot2u(xr[i][1], q0.y, e);
        e = fdot2u(xr[i][2], q0.z, e); e = fdot2u(xr[i][3], q0.w, e);
        e = fdot2u(xr[i][4], q1.x, e); e = fdot2u(xr[i][5], q1.y, e);
        e = fdot2u(xr[i][6], q1.z, e); e = fdot2u(xr[i][7], q1.w, e);
        ep[i] = e;
      }
    }
    // cross-wave reduction, chunk A (n < 512)
    #pragma unroll
    for (int i = 0; i < 8; ++i) sm.epart[w][i*64 + l] = ep[i];
    __syncthreads();                              // B3
    float e0 = 0.f;
    #pragma unroll
    for (int ww = 0; ww < 8; ++ww) e0 += sm.epart[ww][tid];
    __syncthreads();                              // B4: chunk A consumed
    #pragma unroll
    for (int i = 0; i < 8; ++i) sm.epart[w][i*64 + l] = ep[i+8];
    __syncthreads();                              // B5
    float e1 = 0.f;
    #pragma unroll
    for (int ww = 0; ww < 8; ++ww) e1 += sm.epart[ww][tid];
    // ---- softmax over 1024 (thread tid owns e[tid], e[512+tid]) ----
    float m = fmaxf(e0, e1);
    #pragma unroll
    for (int off = 32; off > 0; off >>= 1) m = fmaxf(m, __shfl_xor(m, off, 64));
    if (l == 0) sm.redm[w] = m;
    __syncthreads();                              // B6
    float M = sm.redm[0];
    #pragma unroll
    for (int ww = 1; ww < 8; ++ww) M = fmaxf(M, sm.redm[ww]);
    float p0 = __expf(e0 - M), p1 = __expf(e1 - M);
    sm.p[tid] = p0; sm.p[512 + tid] = p1;
    float s = p0 + p1;
    #pragma unroll
    for (int off = 32; off > 0; off >>= 1) s += __shfl_xor(s, off, 64);
    if (l == 0) sm.reds[w] = s;
    __syncthreads();                              // B7: p + sums visible
    float S = 0.f;
    #pragma unroll
    for (int ww = 0; ww < 8; ++ww) S += sm.reds[ww];
    float inv = 1.0f / S;
    // ---- r[d] = (1/S) * sum_n p[n] x[n][d] over own d-slice ----
    float racc[16];
    #pragma unroll
    for (int k = 0; k < 16; ++k) racc[k] = 0.f;
    #pragma unroll
    for (int i = 0; i < 16; ++i){
      float pi = sm.p[i*64 + l];
      #pragma unroll
      for (int j = 0; j < 8; ++j){
        h2f xv = __builtin_bit_cast(h2f, xr[i][j]);
        racc[2*j]   += pi * (float)xv[0];
        racc[2*j+1] += pi * (float)xv[1];
      }
    }
    #pragma unroll
    for (int k = 0; k < 16; ++k){
      #pragma unroll
      for (int off = 32; off > 0; off >>= 1) racc[k] += __shfl_xor(racc[k], off, 64);
    }
    if (l < 16){
      float v = racc[0];
      #pragma unroll
      for (int k = 1; k < 16; ++k) v = (l == k) ? racc[k] : v;
      v *= inv;
      sm.r[16*w + l]  = v;
      sm.r2a[16*w + l] = (_Float16)v;
    }
    __syncthreads();                              // B8: r ready for next step
  }

  // ---- out[b][o] = q_star · W_lin[o] + b_lin[o] ----
  if (tid < 256){
    const float4* wrow = (const float4*)(Wlin + (size_t)tid*256);
    float acc = blin[tid];
    #pragma unroll 8
    for (int k4 = 0; k4 < 32; ++k4){
      float4 a = wrow[k4];
      float4 v = *(const float4*)&sm.h[4*k4];
      acc += a.x*v.x + a.y*v.y + a.z*v.z + a.w*v.w;
    }
    #pragma unroll 8
    for (int k4 = 0; k4 < 32; ++k4){
      float4 a = wrow[32 + k4];
      float4 v = *(const float4*)&sm.r[4*k4];
      acc += a.x*v.x + a.y*v.y + a.z*v.z + a.w*v.w;
    }
    out[(size_t)b*256 + tid] = acc;
  }
}

extern "C" void kernel_launch(void* const* d_in, const int* in_sizes, int n_in,
                              void* d_out, int out_size, void* d_ws, size_t ws_size,
                              hipStream_t stream)
{
  (void)in_sizes; (void)n_in; (void)out_size;
  const float* x    = (const float*)d_in[0];
  const float* Wih  = (const float*)d_in[1];
  const float* Whh  = (const float*)d_in[2];
  const float* bih  = (const float*)d_in[3];
  const float* bhh  = (const float*)d_in[4];
  const float* Wlin = (const float*)d_in[5];
  const float* blin = (const float*)d_in[6];
  float* out = (float*)d_out;

  uint32_t* w2cm = (uint32_t*)d_ws;
  int usew2 = (ws_size >= (size_t)(64*512*4)) ? 1 : 0;
  if (usew2){
    prep_w2_kernel<<<64, 512, 0, stream>>>(Wih, w2cm);
  }
  s2s_kernel<<<256, 512, 0, stream>>>(x, Wih, Whh, bih, bhh, Wlin, blin, w2cm, usew2, out);
}

// Round 3
// 69769.489 us; speedup vs baseline: 1.3128x; 1.3128x over previous
//
#include <hip/hip_runtime.h>
#include <stdint.h>

// Set2Set encoder, MI355X.
// Round 2 fix: r1 spilled xr[16][8] to scratch (VGPR_Count=128 = allocator's
// 4-waves/EU heuristic; WRITE_SIZE 256MB of spill writes, FETCH 90GB of spill
// re-reads, VALUBusy 3.4%). LDS=152KB forces 1 block/CU = 2 waves/EU anyway,
// so clamp amdgpu_waves_per_eu(2,2) -> 256 VGPR budget, xr stays in registers.
// Design: 1 block per batch element (256 blocks = 1/CU), 512 threads (8 waves).
//  - x[b] pinned in VGPRs as f16 pairs: xr[16][8] u32 = 128 VGPRs/thread.
//    wave w owns d-slice [16w,16w+16); lane l owns rows {64i+l, i=0..15}.
//  - W1 = W_ih[:, :128] + W_hh folded to f16, column-major in LDS (128 KB).
//  - W2 = W_ih[:, 128:] as f16x2 column-major in d_ws (prep kernel), L2-resident
//    per-step reads (128 KB/XCD working set).
//  - e/softmax/r fully on-chip; cross-wave e-reduce via 16 KB LDS in 2 chunks.

typedef _Float16 h2f __attribute__((ext_vector_type(2)));

#ifndef __has_builtin
#define __has_builtin(x) 0
#endif

__device__ __forceinline__ uint32_t pack_h2(float a, float b){
  h2f v; v[0] = (_Float16)a; v[1] = (_Float16)b;
  return __builtin_bit_cast(uint32_t, v);
}

__device__ __forceinline__ float fdot2u(uint32_t a, uint32_t b, float c){
  h2f ah = __builtin_bit_cast(h2f, a), bh = __builtin_bit_cast(h2f, b);
#if __has_builtin(__builtin_amdgcn_fdot2)
  return __builtin_amdgcn_fdot2(ah, bh, c, false);
#else
  return c + (float)ah[0]*(float)bh[0] + (float)ah[1]*(float)bh[1];
#endif
}

__device__ __forceinline__ float sigmoidf_(float x){
  return 1.0f / (1.0f + __expf(-x));
}

struct SMem {
  uint32_t w1[64][512];          // 128 KB: W1 f16x2, column-major: w1[kp][j]
  float epart[8][512];           // 16 KB: cross-wave e partials (2 chunks)
  float p[1024];                 // 4 KB: softmax numerators
  float g[512];                  // gates
  float h[128];
  float r[128];
  alignas(16) _Float16 h2a[128]; // packed f16 copy of h (q)
  alignas(16) _Float16 r2a[128]; // packed f16 copy of r
  float redm[8];
  float reds[8];
};                               // ~152 KB total (< 160 KB)

__global__ void prep_w2_kernel(const float* __restrict__ Wih, uint32_t* __restrict__ w2cm){
  int idx = blockIdx.x * blockDim.x + threadIdx.x;   // 64*512 entries
  if (idx < 64*512){
    int kp = idx >> 9, j = idx & 511;
    w2cm[idx] = pack_h2(Wih[j*256 + 128 + 2*kp], Wih[j*256 + 128 + 2*kp + 1]);
  }
}

__global__
__attribute__((amdgpu_flat_work_group_size(512, 512)))
__attribute__((amdgpu_waves_per_eu(2, 2)))
void s2s_kernel(const float* __restrict__ x, const float* __restrict__ Wih,
                const float* __restrict__ Whh, const float* __restrict__ bih,
                const float* __restrict__ bhh, const float* __restrict__ Wlin,
                const float* __restrict__ blin, const uint32_t* __restrict__ w2cm,
                int usew2, float* __restrict__ out)
{
  __shared__ SMem sm;
  const int tid = threadIdx.x;
  const int w = tid >> 6, l = tid & 63;
  const int b = blockIdx.x;

  // ---- load x[b] into registers as f16 pairs (one-time HBM read) ----
  uint32_t xr[16][8];
  {
    const float* xb = x + (size_t)b*1024*128 + 16*w;
    #pragma unroll
    for (int i = 0; i < 16; ++i){
      const float* row = xb + (size_t)(i*64 + l)*128;
      #pragma unroll
      for (int j = 0; j < 8; ++j){
        float2 v = *(const float2*)(row + 2*j);
        xr[i][j] = pack_h2(v.x, v.y);
      }
    }
  }
  // ---- fold W1 = W_ih[:, :128] + W_hh into LDS (f16x2, column-major) ----
  {
    const float* wi = Wih + (size_t)tid*256;
    const float* wh = Whh + (size_t)tid*128;
    #pragma unroll 8
    for (int kp = 0; kp < 64; ++kp){
      sm.w1[kp][tid] = pack_h2(wi[2*kp] + wh[2*kp], wi[2*kp+1] + wh[2*kp+1]);
    }
  }
  const float biasj = bih[tid] + bhh[tid];
  if (tid < 128){
    sm.h[tid] = 0.f; sm.r[tid] = 0.f;
    sm.h2a[tid] = (_Float16)0.f; sm.r2a[tid] = (_Float16)0.f;
  }
  float creg = 0.f;   // LSTM cell state, owned by threads 0..127
  __syncthreads();

  #pragma unroll 1
  for (int t = 0; t < 1024; ++t){
    // ---- gates[j] = biasj + W1[j]·h + W2[j]·r  (thread tid = gate j) ----
    float acc = biasj;
    {
      const uint4* hp = (const uint4*)sm.h2a;   // broadcast reads
      #pragma unroll 4
      for (int k8 = 0; k8 < 16; ++k8){
        uint4 hv = hp[k8];
        acc = fdot2u(sm.w1[4*k8+0][tid], hv.x, acc);
        acc = fdot2u(sm.w1[4*k8+1][tid], hv.y, acc);
        acc = fdot2u(sm.w1[4*k8+2][tid], hv.z, acc);
        acc = fdot2u(sm.w1[4*k8+3][tid], hv.w, acc);
      }
    }
    if (usew2){
      const uint4* rp = (const uint4*)sm.r2a;
      #pragma unroll 4
      for (int k8 = 0; k8 < 16; ++k8){
        uint4 rv = rp[k8];
        acc = fdot2u(w2cm[(4*k8+0)*512 + tid], rv.x, acc);
        acc = fdot2u(w2cm[(4*k8+1)*512 + tid], rv.y, acc);
        acc = fdot2u(w2cm[(4*k8+2)*512 + tid], rv.z, acc);
        acc = fdot2u(w2cm[(4*k8+3)*512 + tid], rv.w, acc);
      }
    } else {
      const float* wi2 = Wih + (size_t)tid*256 + 128;
      #pragma unroll 4
      for (int kp = 0; kp < 64; ++kp){
        float2 wv = *(const float2*)(wi2 + 2*kp);
        acc += wv.x*sm.r[2*kp] + wv.y*sm.r[2*kp+1];
      }
    }
    sm.g[tid] = acc;
    __syncthreads();                              // B1: gates visible
    // ---- LSTM pointwise (PyTorch gate order i,f,g,o) ----
    if (tid < 128){
      float gi = sm.g[tid], gf = sm.g[128+tid], gc = sm.g[256+tid], go = sm.g[384+tid];
      creg = sigmoidf_(gf)*creg + sigmoidf_(gi)*tanhf(gc);
      float hh = sigmoidf_(go)*tanhf(creg);
      sm.h[tid]  = hh;
      sm.h2a[tid] = (_Float16)hh;
    }
    __syncthreads();                              // B2: h, h2a visible
    // ---- e[n] = x[n]·q : per-thread partials over own d-slice ----
    float ep[16];
    {
      uint4 q0 = *(const uint4*)&sm.h2a[16*w];
      uint4 q1 = *(const uint4*)&sm.h2a[16*w + 8];
      #pragma unroll
      for (int i = 0; i < 16; ++i){
        float e = 0.f;
        e = fdot2u(xr[i][0], q0.x, e); e = fdot2u(xr[i][1], q0.y, e);
        e = fdot2u(xr[i][2], q0.z, e); e = fdot2u(xr[i][3], q0.w, e);
        e = fdot2u(xr[i][4], q1.x, e); e = fdot2u(xr[i][5], q1.y, e);
        e = fdot2u(xr[i][6], q1.z, e); e = fdot2u(xr[i][7], q1.w, e);
        ep[i] = e;
      }
    }
    // cross-wave reduction, chunk A (n < 512)
    #pragma unroll
    for (int i = 0; i < 8; ++i) sm.epart[w][i*64 + l] = ep[i];
    __syncthreads();                              // B3
    float e0 = 0.f;
    #pragma unroll
    for (int ww = 0; ww < 8; ++ww) e0 += sm.epart[ww][tid];
    __syncthreads();                              // B4: chunk A consumed
    #pragma unroll
    for (int i = 0; i < 8; ++i) sm.epart[w][i*64 + l] = ep[i+8];
    __syncthreads();                              // B5
    float e1 = 0.f;
    #pragma unroll
    for (int ww = 0; ww < 8; ++ww) e1 += sm.epart[ww][tid];
    // ---- softmax over 1024 (thread tid owns e[tid], e[512+tid]) ----
    float m = fmaxf(e0, e1);
    #pragma unroll
    for (int off = 32; off > 0; off >>= 1) m = fmaxf(m, __shfl_xor(m, off, 64));
    if (l == 0) sm.redm[w] = m;
    __syncthreads();                              // B6
    float M = sm.redm[0];
    #pragma unroll
    for (int ww = 1; ww < 8; ++ww) M = fmaxf(M, sm.redm[ww]);
    float p0 = __expf(e0 - M), p1 = __expf(e1 - M);
    sm.p[tid] = p0; sm.p[512 + tid] = p1;
    float s = p0 + p1;
    #pragma unroll
    for (int off = 32; off > 0; off >>= 1) s += __shfl_xor(s, off, 64);
    if (l == 0) sm.reds[w] = s;
    __syncthreads();                              // B7: p + sums visible
    float S = 0.f;
    #pragma unroll
    for (int ww = 0; ww < 8; ++ww) S += sm.reds[ww];
    float inv = 1.0f / S;
    // ---- r[d] = (1/S) * sum_n p[n] x[n][d] over own d-slice ----
    float racc[16];
    #pragma unroll
    for (int k = 0; k < 16; ++k) racc[k] = 0.f;
    #pragma unroll
    for (int i = 0; i < 16; ++i){
      float pi = sm.p[i*64 + l];
      #pragma unroll
      for (int j = 0; j < 8; ++j){
        h2f xv = __builtin_bit_cast(h2f, xr[i][j]);
        racc[2*j]   += pi * (float)xv[0];
        racc[2*j+1] += pi * (float)xv[1];
      }
    }
    #pragma unroll
    for (int k = 0; k < 16; ++k){
      #pragma unroll
      for (int off = 32; off > 0; off >>= 1) racc[k] += __shfl_xor(racc[k], off, 64);
    }
    if (l < 16){
      float v = racc[0];
      #pragma unroll
      for (int k = 1; k < 16; ++k) v = (l == k) ? racc[k] : v;
      v *= inv;
      sm.r[16*w + l]  = v;
      sm.r2a[16*w + l] = (_Float16)v;
    }
    __syncthreads();                              // B8: r ready for next step
  }

  // ---- out[b][o] = q_star · W_lin[o] + b_lin[o] ----
  if (tid < 256){
    const float4* wrow = (const float4*)(Wlin + (size_t)tid*256);
    float acc = blin[tid];
    #pragma unroll 8
    for (int k4 = 0; k4 < 32; ++k4){
      float4 a = wrow[k4];
      float4 v = *(const float4*)&sm.h[4*k4];
      acc += a.x*v.x + a.y*v.y + a.z*v.z + a.w*v.w;
    }
    #pragma unroll 8
    for (int k4 = 0; k4 < 32; ++k4){
      float4 a = wrow[32 + k4];
      float4 v = *(const float4*)&sm.r[4*k4];
      acc += a.x*v.x + a.y*v.y + a.z*v.z + a.w*v.w;
    }
    out[(size_t)b*256 + tid] = acc;
  }
}

extern "C" void kernel_launch(void* const* d_in, const int* in_sizes, int n_in,
                              void* d_out, int out_size, void* d_ws, size_t ws_size,
                              hipStream_t stream)
{
  (void)in_sizes; (void)n_in; (void)out_size;
  const float* x    = (const float*)d_in[0];
  const float* Wih  = (const float*)d_in[1];
  const float* Whh  = (const float*)d_in[2];
  const float* bih  = (const float*)d_in[3];
  const float* bhh  = (const float*)d_in[4];
  const float* Wlin = (const float*)d_in[5];
  const float* blin = (const float*)d_in[6];
  float* out = (float*)d_out;

  uint32_t* w2cm = (uint32_t*)d_ws;
  int usew2 = (ws_size >= (size_t)(64*512*4)) ? 1 : 0;
  if (usew2){
    prep_w2_kernel<<<64, 512, 0, stream>>>(Wih, w2cm);
  }
  s2s_kernel<<<256, 512, 0, stream>>>(x, Wih, Whh, bih, bhh, Wlin, blin, w2cm, usew2, out);
}

// Round 5
// 66913.147 us; speedup vs baseline: 1.3688x; 1.0427x over previous
//
#include <hip/hip_runtime.h>
#include <stdint.h>

// Set2Set encoder, MI355X.
// R4 = bisect round: EXACT R2 kernel (proven correct, absmax 7.8e-3) with ONE
// change: occupancy attrs -> __launch_bounds__(512, 1).
// Model from R1-R3: hipcc's launch_bounds 2nd arg behaves as min BLOCKS/CU
// (R1: (512,2) -> 2 blk * 8 waves = 4 w/SIMD -> VGPR budget exactly 128, as
// observed). (512,1) -> 1 blk/CU = 2 w/SIMD -> budget 256, enough for
// xr[16][8] (128 VGPRs) + working set (~100) without scratch spill.
// R3's NaN had 3 confounded code changes; W2->regs retried next round alone.

typedef _Float16 h2f __attribute__((ext_vector_type(2)));

#ifndef __has_builtin
#define __has_builtin(x) 0
#endif

__device__ __forceinline__ uint32_t pack_h2(float a, float b){
  h2f v; v[0] = (_Float16)a; v[1] = (_Float16)b;
  return __builtin_bit_cast(uint32_t, v);
}

__device__ __forceinline__ float fdot2u(uint32_t a, uint32_t b, float c){
  h2f ah = __builtin_bit_cast(h2f, a), bh = __builtin_bit_cast(h2f, b);
#if __has_builtin(__builtin_amdgcn_fdot2)
  return __builtin_amdgcn_fdot2(ah, bh, c, false);
#else
  return c + (float)ah[0]*(float)bh[0] + (float)ah[1]*(float)bh[1];
#endif
}

__device__ __forceinline__ float sigmoidf_(float x){
  return 1.0f / (1.0f + __expf(-x));
}

struct SMem {
  uint32_t w1[64][512];          // 128 KB: W1 f16x2, column-major: w1[kp][j]
  float epart[8][512];           // 16 KB: cross-wave e partials (2 chunks)
  float p[1024];                 // 4 KB: softmax numerators
  float g[512];                  // gates
  float h[128];
  float r[128];
  alignas(16) _Float16 h2a[128]; // packed f16 copy of h (q)
  alignas(16) _Float16 r2a[128]; // packed f16 copy of r
  float redm[8];
  float reds[8];
};                               // ~152 KB total (< 160 KB)

__global__ void prep_w2_kernel(const float* __restrict__ Wih, uint32_t* __restrict__ w2cm){
  int idx = blockIdx.x * blockDim.x + threadIdx.x;   // 64*512 entries
  if (idx < 64*512){
    int kp = idx >> 9, j = idx & 511;
    w2cm[idx] = pack_h2(Wih[j*256 + 128 + 2*kp], Wih[j*256 + 128 + 2*kp + 1]);
  }
}

__global__ __launch_bounds__(512, 1)
void s2s_kernel(const float* __restrict__ x, const float* __restrict__ Wih,
                const float* __restrict__ Whh, const float* __restrict__ bih,
                const float* __restrict__ bhh, const float* __restrict__ Wlin,
                const float* __restrict__ blin, const uint32_t* __restrict__ w2cm,
                int usew2, float* __restrict__ out)
{
  __shared__ SMem sm;
  const int tid = threadIdx.x;
  const int w = tid >> 6, l = tid & 63;
  const int b = blockIdx.x;

  // ---- load x[b] into registers as f16 pairs (one-time HBM read) ----
  uint32_t xr[16][8];
  {
    const float* xb = x + (size_t)b*1024*128 + 16*w;
    #pragma unroll
    for (int i = 0; i < 16; ++i){
      const float* row = xb + (size_t)(i*64 + l)*128;
      #pragma unroll
      for (int j = 0; j < 8; ++j){
        float2 v = *(const float2*)(row + 2*j);
        xr[i][j] = pack_h2(v.x, v.y);
      }
    }
  }
  // ---- fold W1 = W_ih[:, :128] + W_hh into LDS (f16x2, column-major) ----
  {
    const float* wi = Wih + (size_t)tid*256;
    const float* wh = Whh + (size_t)tid*128;
    #pragma unroll 8
    for (int kp = 0; kp < 64; ++kp){
      sm.w1[kp][tid] = pack_h2(wi[2*kp] + wh[2*kp], wi[2*kp+1] + wh[2*kp+1]);
    }
  }
  const float biasj = bih[tid] + bhh[tid];
  if (tid < 128){
    sm.h[tid] = 0.f; sm.r[tid] = 0.f;
    sm.h2a[tid] = (_Float16)0.f; sm.r2a[tid] = (_Float16)0.f;
  }
  float creg = 0.f;   // LSTM cell state, owned by threads 0..127
  __syncthreads();

  #pragma unroll 1
  for (int t = 0; t < 1024; ++t){
    // ---- gates[j] = biasj + W1[j]·h + W2[j]·r  (thread tid = gate j) ----
    float acc = biasj;
    {
      const uint4* hp = (const uint4*)sm.h2a;   // broadcast reads
      #pragma unroll 4
      for (int k8 = 0; k8 < 16; ++k8){
        uint4 hv = hp[k8];
        acc = fdot2u(sm.w1[4*k8+0][tid], hv.x, acc);
        acc = fdot2u(sm.w1[4*k8+1][tid], hv.y, acc);
        acc = fdot2u(sm.w1[4*k8+2][tid], hv.z, acc);
        acc = fdot2u(sm.w1[4*k8+3][tid], hv.w, acc);
      }
    }
    if (usew2){
      const uint4* rp = (const uint4*)sm.r2a;
      #pragma unroll 4
      for (int k8 = 0; k8 < 16; ++k8){
        uint4 rv = rp[k8];
        acc = fdot2u(w2cm[(4*k8+0)*512 + tid], rv.x, acc);
        acc = fdot2u(w2cm[(4*k8+1)*512 + tid], rv.y, acc);
        acc = fdot2u(w2cm[(4*k8+2)*512 + tid], rv.z, acc);
        acc = fdot2u(w2cm[(4*k8+3)*512 + tid], rv.w, acc);
      }
    } else {
      const float* wi2 = Wih + (size_t)tid*256 + 128;
      #pragma unroll 4
      for (int kp = 0; kp < 64; ++kp){
        float2 wv = *(const float2*)(wi2 + 2*kp);
        acc += wv.x*sm.r[2*kp] + wv.y*sm.r[2*kp+1];
      }
    }
    sm.g[tid] = acc;
    __syncthreads();                              // B1: gates visible
    // ---- LSTM pointwise (PyTorch gate order i,f,g,o) ----
    if (tid < 128){
      float gi = sm.g[tid], gf = sm.g[128+tid], gc = sm.g[256+tid], go = sm.g[384+tid];
      creg = sigmoidf_(gf)*creg + sigmoidf_(gi)*tanhf(gc);
      float hh = sigmoidf_(go)*tanhf(creg);
      sm.h[tid]  = hh;
      sm.h2a[tid] = (_Float16)hh;
    }
    __syncthreads();                              // B2: h, h2a visible
    // ---- e[n] = x[n]·q : per-thread partials over own d-slice ----
    float ep[16];
    {
      uint4 q0 = *(const uint4*)&sm.h2a[16*w];
      uint4 q1 = *(const uint4*)&sm.h2a[16*w + 8];
      #pragma unroll
      for (int i = 0; i < 16; ++i){
        float e = 0.f;
        e = fdot2u(xr[i][0], q0.x, e); e = fdot2u(xr[i][1], q0.y, e);
        e = fdot2u(xr[i][2], q0.z, e); e = fdot2u(xr[i][3], q0.w, e);
        e = fdot2u(xr[i][4], q1.x, e); e = fdot2u(xr[i][5], q1.y, e);
        e = fdot2u(xr[i][6], q1.z, e); e = fdot2u(xr[i][7], q1.w, e);
        ep[i] = e;
      }
    }
    // cross-wave reduction, chunk A (n < 512)
    #pragma unroll
    for (int i = 0; i < 8; ++i) sm.epart[w][i*64 + l] = ep[i];
    __syncthreads();                              // B3
    float e0 = 0.f;
    #pragma unroll
    for (int ww = 0; ww < 8; ++ww) e0 += sm.epart[ww][tid];
    __syncthreads();                              // B4: chunk A consumed
    #pragma unroll
    for (int i = 0; i < 8; ++i) sm.epart[w][i*64 + l] = ep[i+8];
    __syncthreads();                              // B5
    float e1 = 0.f;
    #pragma unroll
    for (int ww = 0; ww < 8; ++ww) e1 += sm.epart[ww][tid];
    // ---- softmax over 1024 (thread tid owns e[tid], e[512+tid]) ----
    float m = fmaxf(e0, e1);
    #pragma unroll
    for (int off = 32; off > 0; off >>= 1) m = fmaxf(m, __shfl_xor(m, off, 64));
    if (l == 0) sm.redm[w] = m;
    __syncthreads();                              // B6
    float M = sm.redm[0];
    #pragma unroll
    for (int ww = 1; ww < 8; ++ww) M = fmaxf(M, sm.redm[ww]);
    float p0 = __expf(e0 - M), p1 = __expf(e1 - M);
    sm.p[tid] = p0; sm.p[512 + tid] = p1;
    float s = p0 + p1;
    #pragma unroll
    for (int off = 32; off > 0; off >>= 1) s += __shfl_xor(s, off, 64);
    if (l == 0) sm.reds[w] = s;
    __syncthreads();                              // B7: p + sums visible
    float S = 0.f;
    #pragma unroll
    for (int ww = 0; ww < 8; ++ww) S += sm.reds[ww];
    float inv = 1.0f / S;
    // ---- r[d] = (1/S) * sum_n p[n] x[n][d] over own d-slice ----
    float racc[16];
    #pragma unroll
    for (int k = 0; k < 16; ++k) racc[k] = 0.f;
    #pragma unroll
    for (int i = 0; i < 16; ++i){
      float pi = sm.p[i*64 + l];
      #pragma unroll
      for (int j = 0; j < 8; ++j){
        h2f xv = __builtin_bit_cast(h2f, xr[i][j]);
        racc[2*j]   += pi * (float)xv[0];
        racc[2*j+1] += pi * (float)xv[1];
      }
    }
    #pragma unroll
    for (int k = 0; k < 16; ++k){
      #pragma unroll
      for (int off = 32; off > 0; off >>= 1) racc[k] += __shfl_xor(racc[k], off, 64);
    }
    if (l < 16){
      float v = racc[0];
      #pragma unroll
      for (int k = 1; k < 16; ++k) v = (l == k) ? racc[k] : v;
      v *= inv;
      sm.r[16*w + l]  = v;
      sm.r2a[16*w + l] = (_Float16)v;
    }
    __syncthreads();                              // B8: r ready for next step
  }

  // ---- out[b][o] = q_star · W_lin[o] + b_lin[o] ----
  if (tid < 256){
    const float4* wrow = (const float4*)(Wlin + (size_t)tid*256);
    float acc = blin[tid];
    #pragma unroll 8
    for (int k4 = 0; k4 < 32; ++k4){
      float4 a = wrow[k4];
      float4 v = *(const float4*)&sm.h[4*k4];
      acc += a.x*v.x + a.y*v.y + a.z*v.z + a.w*v.w;
    }
    #pragma unroll 8
    for (int k4 = 0; k4 < 32; ++k4){
      float4 a = wrow[32 + k4];
      float4 v = *(const float4*)&sm.r[4*k4];
      acc += a.x*v.x + a.y*v.y + a.z*v.z + a.w*v.w;
    }
    out[(size_t)b*256 + tid] = acc;
  }
}

extern "C" void kernel_launch(void* const* d_in, const int* in_sizes, int n_in,
                              void* d_out, int out_size, void* d_ws, size_t ws_size,
                              hipStream_t stream)
{
  (void)in_sizes; (void)n_in; (void)out_size;
  const float* x    = (const float*)d_in[0];
  const float* Wih  = (const float*)d_in[1];
  const float* Whh  = (const float*)d_in[2];
  const float* bih  = (const float*)d_in[3];
  const float* bhh  = (const float*)d_in[4];
  const float* Wlin = (const float*)d_in[5];
  const float* blin = (const float*)d_in[6];
  float* out = (float*)d_out;

  uint32_t* w2cm = (uint32_t*)d_ws;
  int usew2 = (ws_size >= (size_t)(64*512*4)) ? 1 : 0;
  if (usew2){
    prep_w2_kernel<<<64, 512, 0, stream>>>(Wih, w2cm);
  }
  s2s_kernel<<<256, 512, 0, stream>>>(x, Wih, Whh, bih, bhh, Wlin, blin, w2cm, usew2, out);
}

// Round 7
// 48281.281 us; speedup vs baseline: 1.8971x; 1.3859x over previous
//
#include <hip/hip_runtime.h>
#include <stdint.h>

// Set2Set encoder, MI355X.  (R6: unchanged resubmit — R5 bench was an infra
// GPUAcquisitionTimeout; no data on this kernel yet.)
// R5: R1/R2/R4 proved the toolchain pins this kernel at VGPR_Count=128
// regardless of launch_bounds(512,2)/(512,1)/amdgpu_waves_per_eu(2,2)
// -> xr[16][8] (128 regs) inevitably spilled (WRITE 162MB, FETCH 53GB).
// Fix: fit UNDER the 128 cap. 1024 threads (16 waves), wave owns 8 cols:
// xr[16][4] = 64 VGPRs. Gate matvec split-k across thread halves.
// All other structure = proven R2 (absmax 7.8e-3), re-indexed.

typedef _Float16 h2f __attribute__((ext_vector_type(2)));

#ifndef __has_builtin
#define __has_builtin(x) 0
#endif

__device__ __forceinline__ uint32_t pack_h2(float a, float b){
  h2f v; v[0] = (_Float16)a; v[1] = (_Float16)b;
  return __builtin_bit_cast(uint32_t, v);
}

__device__ __forceinline__ float fdot2u(uint32_t a, uint32_t b, float c){
  h2f ah = __builtin_bit_cast(h2f, a), bh = __builtin_bit_cast(h2f, b);
#if __has_builtin(__builtin_amdgcn_fdot2)
  return __builtin_amdgcn_fdot2(ah, bh, c, false);
#else
  return c + (float)ah[0]*(float)bh[0] + (float)ah[1]*(float)bh[1];
#endif
}

__device__ __forceinline__ float sigmoidf_(float x){
  return 1.0f / (1.0f + __expf(-x));
}

struct SMem {
  uint32_t w1[64][512];          // 128 KB: W1 f16x2, column-major: w1[kp][j]
  float epart[16][256];          // 16 KB: cross-wave e partials (4 chunks)
  float gpart[2][512];           // 4 KB: split-k gate partials
  float p[1024];                 // 4 KB: softmax numerators
  float h[128];
  float r[128];
  alignas(16) _Float16 h2a[128]; // packed f16 copy of h (q)
  alignas(16) _Float16 r2a[128]; // packed f16 copy of r
  float redm[4];
  float reds[4];
};                               // ~153.5 KB (< 160 KB)

__global__ void prep_w2_kernel(const float* __restrict__ Wih, uint32_t* __restrict__ w2cm){
  int idx = blockIdx.x * blockDim.x + threadIdx.x;   // 64*512 entries
  if (idx < 64*512){
    int kp = idx >> 9, j = idx & 511;
    w2cm[idx] = pack_h2(Wih[j*256 + 128 + 2*kp], Wih[j*256 + 128 + 2*kp + 1]);
  }
}

__global__ __launch_bounds__(1024, 1)
void s2s_kernel(const float* __restrict__ x, const float* __restrict__ Wih,
                const float* __restrict__ Whh, const float* __restrict__ bih,
                const float* __restrict__ bhh, const float* __restrict__ Wlin,
                const float* __restrict__ blin, const uint32_t* __restrict__ w2cm,
                int usew2, float* __restrict__ out)
{
  __shared__ SMem sm;
  const int tid  = threadIdx.x;
  const int w    = tid >> 6, l = tid & 63;   // wave 0..15, lane 0..63
  const int j    = tid & 511;                // gate index
  const int half = tid >> 9;                 // split-k half 0/1
  const int b    = blockIdx.x;

  // ---- load x[b] cols [8w,8w+8) into registers as f16 pairs ----
  uint32_t xr[16][4];                        // 64 VGPRs
  {
    const float* xb = x + (size_t)b*1024*128 + 8*w;
    #pragma unroll
    for (int i = 0; i < 16; ++i){
      const float* row = xb + (size_t)(i*64 + l)*128;
      float4 a = *(const float4*)(row);
      float4 c = *(const float4*)(row + 4);
      xr[i][0] = pack_h2(a.x, a.y); xr[i][1] = pack_h2(a.z, a.w);
      xr[i][2] = pack_h2(c.x, c.y); xr[i][3] = pack_h2(c.z, c.w);
    }
  }
  // ---- fold W1 = W_ih[:, :128] + W_hh into LDS (f16x2, column-major) ----
  {
    const float* wi = Wih + (size_t)j*256;
    const float* wh = Whh + (size_t)j*128;
    const int kb = half*32;
    #pragma unroll 4
    for (int kk = 0; kk < 32; ++kk){
      int kp = kb + kk;
      sm.w1[kp][j] = pack_h2(wi[2*kp] + wh[2*kp], wi[2*kp+1] + wh[2*kp+1]);
    }
  }
  const float biasj = bih[j] + bhh[j];
  if (tid < 128){
    sm.h[tid] = 0.f; sm.r[tid] = 0.f;
    sm.h2a[tid] = (_Float16)0.f; sm.r2a[tid] = (_Float16)0.f;
  }
  float creg = 0.f;   // LSTM cell state, valid for tid<128
  __syncthreads();

  #pragma unroll 1
  for (int t = 0; t < 1024; ++t){
    // ---- gate partial: thread (j,half) does half the k-dim ----
    float acc = (half == 0) ? biasj : 0.f;
    {
      const uint4* hq = (const uint4*)sm.h2a;    // wave-uniform broadcasts
      #pragma unroll 4
      for (int q = 0; q < 8; ++q){
        uint4 hv = hq[half*8 + q];
        int kp = half*32 + 4*q;
        acc = fdot2u(sm.w1[kp+0][j], hv.x, acc);
        acc = fdot2u(sm.w1[kp+1][j], hv.y, acc);
        acc = fdot2u(sm.w1[kp+2][j], hv.z, acc);
        acc = fdot2u(sm.w1[kp+3][j], hv.w, acc);
      }
    }
    if (usew2){
      const uint4* rq = (const uint4*)sm.r2a;
      #pragma unroll 4
      for (int q = 0; q < 8; ++q){
        uint4 rv = rq[half*8 + q];
        int kp = half*32 + 4*q;
        acc = fdot2u(w2cm[(kp+0)*512 + j], rv.x, acc);
        acc = fdot2u(w2cm[(kp+1)*512 + j], rv.y, acc);
        acc = fdot2u(w2cm[(kp+2)*512 + j], rv.z, acc);
        acc = fdot2u(w2cm[(kp+3)*512 + j], rv.w, acc);
      }
    } else {
      const float* wi2 = Wih + (size_t)j*256 + 128 + half*64;
      #pragma unroll 4
      for (int kk = 0; kk < 32; ++kk){
        float2 wv = *(const float2*)(wi2 + 2*kk);
        acc += wv.x*sm.r[half*64 + 2*kk] + wv.y*sm.r[half*64 + 2*kk+1];
      }
    }
    sm.gpart[half][j] = acc;
    __syncthreads();                              // B1: gate partials visible
    // ---- LSTM pointwise (PyTorch gate order i,f,g,o) ----
    if (tid < 128){
      float gi = sm.gpart[0][tid]     + sm.gpart[1][tid];
      float gf = sm.gpart[0][128+tid] + sm.gpart[1][128+tid];
      float gc = sm.gpart[0][256+tid] + sm.gpart[1][256+tid];
      float go = sm.gpart[0][384+tid] + sm.gpart[1][384+tid];
      creg = sigmoidf_(gf)*creg + sigmoidf_(gi)*tanhf(gc);
      float hh = sigmoidf_(go)*tanhf(creg);
      sm.h[tid]  = hh;
      sm.h2a[tid] = (_Float16)hh;
    }
    __syncthreads();                              // B2: h, h2a visible
    // ---- e[n] = x[n]·q : 4 chunks of 256 rows through epart ----
    uint4 qv = ((const uint4*)sm.h2a)[w];         // cols [8w,8w+8) of q
    float et[4] = {0.f, 0.f, 0.f, 0.f};
    #pragma unroll
    for (int c = 0; c < 4; ++c){
      #pragma unroll
      for (int ii = 0; ii < 4; ++ii){
        int i = 4*c + ii;
        float e = 0.f;
        e = fdot2u(xr[i][0], qv.x, e);
        e = fdot2u(xr[i][1], qv.y, e);
        e = fdot2u(xr[i][2], qv.z, e);
        e = fdot2u(xr[i][3], qv.w, e);
        sm.epart[w][ii*64 + l] = e;
      }
      __syncthreads();                            // chunk partials visible
      if (tid < 256){
        float tot = 0.f;
        #pragma unroll
        for (int ww = 0; ww < 16; ++ww) tot += sm.epart[ww][tid];
        et[c] = tot;                              // e[256c + tid]
      }
      __syncthreads();                            // chunk consumed
    }
    // ---- softmax over 1024 (tid<256 owns rows 256c+tid, c=0..3) ----
    if (tid < 256){
      float mm = fmaxf(fmaxf(et[0], et[1]), fmaxf(et[2], et[3]));
      #pragma unroll
      for (int off = 32; off > 0; off >>= 1) mm = fmaxf(mm, __shfl_xor(mm, off, 64));
      if (l == 0) sm.redm[w] = mm;
    }
    __syncthreads();                              // B11: wave maxes
    float M = fmaxf(fmaxf(sm.redm[0], sm.redm[1]), fmaxf(sm.redm[2], sm.redm[3]));
    if (tid < 256){
      float p0 = __expf(et[0]-M), p1 = __expf(et[1]-M);
      float p2 = __expf(et[2]-M), p3 = __expf(et[3]-M);
      sm.p[tid] = p0; sm.p[256+tid] = p1; sm.p[512+tid] = p2; sm.p[768+tid] = p3;
      float s = p0 + p1 + p2 + p3;
      #pragma unroll
      for (int off = 32; off > 0; off >>= 1) s += __shfl_xor(s, off, 64);
      if (l == 0) sm.reds[w] = s;
    }
    __syncthreads();                              // B12: p + wave sums
    float inv;
    {
      float S = (sm.reds[0] + sm.reds[1]) + (sm.reds[2] + sm.reds[3]);
      inv = 1.0f / S;
    }
    // ---- r[d] = (1/S) * sum_n p[n] x[n][d], cols [8w,8w+8) ----
    float racc[8];
    #pragma unroll
    for (int k = 0; k < 8; ++k) racc[k] = 0.f;
    #pragma unroll
    for (int i = 0; i < 16; ++i){
      float pi = sm.p[i*64 + l];
      h2f x0 = __builtin_bit_cast(h2f, xr[i][0]);
      h2f x1 = __builtin_bit_cast(h2f, xr[i][1]);
      h2f x2 = __builtin_bit_cast(h2f, xr[i][2]);
      h2f x3 = __builtin_bit_cast(h2f, xr[i][3]);
      racc[0] += pi*(float)x0[0]; racc[1] += pi*(float)x0[1];
      racc[2] += pi*(float)x1[0]; racc[3] += pi*(float)x1[1];
      racc[4] += pi*(float)x2[0]; racc[5] += pi*(float)x2[1];
      racc[6] += pi*(float)x3[0]; racc[7] += pi*(float)x3[1];
    }
    #pragma unroll
    for (int k = 0; k < 8; ++k){
      #pragma unroll
      for (int off = 32; off > 0; off >>= 1) racc[k] += __shfl_xor(racc[k], off, 64);
    }
    if (l < 8){
      float v = racc[0];
      #pragma unroll
      for (int k = 1; k < 8; ++k) v = (l == k) ? racc[k] : v;
      v *= inv;
      sm.r[8*w + l]   = v;
      sm.r2a[8*w + l] = (_Float16)v;
    }
    __syncthreads();                              // B13: r ready for next step
  }

  // ---- out[b][o] = q_star · W_lin[o] + b_lin[o] ----
  if (tid < 256){
    const float4* wrow = (const float4*)(Wlin + (size_t)tid*256);
    float acc = blin[tid];
    #pragma unroll 8
    for (int k4 = 0; k4 < 32; ++k4){
      float4 a = wrow[k4];
      float4 v = *(const float4*)&sm.h[4*k4];
      acc += a.x*v.x + a.y*v.y + a.z*v.z + a.w*v.w;
    }
    #pragma unroll 8
    for (int k4 = 0; k4 < 32; ++k4){
      float4 a = wrow[32 + k4];
      float4 v = *(const float4*)&sm.r[4*k4];
      acc += a.x*v.x + a.y*v.y + a.z*v.z + a.w*v.w;
    }
    out[(size_t)b*256 + tid] = acc;
  }
}

extern "C" void kernel_launch(void* const* d_in, const int* in_sizes, int n_in,
                              void* d_out, int out_size, void* d_ws, size_t ws_size,
                              hipStream_t stream)
{
  (void)in_sizes; (void)n_in; (void)out_size;
  const float* x    = (const float*)d_in[0];
  const float* Wih  = (const float*)d_in[1];
  const float* Whh  = (const float*)d_in[2];
  const float* bih  = (const float*)d_in[3];
  const float* bhh  = (const float*)d_in[4];
  const float* Wlin = (const float*)d_in[5];
  const float* blin = (const float*)d_in[6];
  float* out = (float*)d_out;

  uint32_t* w2cm = (uint32_t*)d_ws;
  int usew2 = (ws_size >= (size_t)(64*512*4)) ? 1 : 0;
  if (usew2){
    prep_w2_kernel<<<64, 512, 0, stream>>>(Wih, w2cm);
  }
  s2s_kernel<<<256, 1024, 0, stream>>>(x, Wih, Whh, bih, bhh, Wlin, blin, w2cm, usew2, out);
}